// Round 13
// baseline (80.255 us; speedup 1.0000x reference)
//
#include <hip/hip_runtime.h>
#include <hip/hip_bf16.h>

// Problem constants (from setup_inputs): price_data float32 [64, 4096, 64]
#define B 64
#define S 4096
#define C 64
#define NCHUNK 16            // s-chunks per batch in K1; block = (b, chunk)
#define LCH (S / NCHUNK)     // 256 s per K1 block
#define RW (LCH / 4)         // 64 rows per wave (4 waves per block)

// native clang vector type (usable with __builtin_nontemporal_store)
typedef float f32x4 __attribute__((ext_vector_type(4)));

// Partials in ws: part[p][ (b*NCHUNK + chunk)*64 + c ], p: 0=sum 1=sumsq
// 2=gain 3=loss 4=sum12 5=sum26
#define PSTRIDE ((size_t)B * NCHUNK * 64)   // 65536 floats per plane (1.5 MB total)

__device__ inline f32x4 vmax0(f32x4 a) {
    f32x4 r;
    r.x = fmaxf(a.x, 0.f);
    r.y = fmaxf(a.y, 0.f);
    r.z = fmaxf(a.z, 0.f);
    r.w = fmaxf(a.w, 0.f);
    return r;
}

__device__ inline f32x4 shfl4(f32x4 v, int src) {
    f32x4 r;
    r.x = __shfl(v.x, src);
    r.y = __shfl(v.y, src);
    r.z = __shfl(v.z, src);
    r.w = __shfl(v.w, src);
    return r;
}

// K1: fused input-copy + partial reductions, wave-contiguous load shape.
// SINGLE CHANGE vs r12: copy stores are PLAIN (cached), not NT. The 64 MB
// copy region fits in L3; scattered 256B chunks get absorbed by the caches
// and write back to HBM lazily, overlapped with K2 (which is fetch-light).
__global__ __launch_bounds__(256) void ti_copy_reduce(const f32x4* __restrict__ in4,
                                                      f32x4* __restrict__ out4,
                                                      float* __restrict__ part) {
    const int b     = blockIdx.x / NCHUNK;
    const int chunk = blockIdx.x % NCHUNK;
    const int tid   = threadIdx.x;
    const int w     = tid >> 6;     // wave 0..3
    const int lane  = tid & 63;
    const int r     = lane >> 4;    // row-in-group 0..3
    const int c4    = lane & 15;    // f4 channel group 0..15
    const int wbase = chunk * LCH + w * RW;   // wave's first row

    const size_t rowbase = (size_t)b * S;

    f32x4 acc[6];
    #pragma unroll
    for (int p = 0; p < 6; ++p) acc[p] = (f32x4){0.f, 0.f, 0.f, 0.f};

    // value of row (wbase-1), channels c4*4..+3 — consumed by r==0 lanes
    f32x4 prev_top = (f32x4){0.f, 0.f, 0.f, 0.f};
    if (wbase > 0) prev_top = in4[(rowbase + wbase - 1) * 16 + c4];

    #pragma unroll 4
    for (int i = 0; i < RW / 4; ++i) {          // 16 iterations
        const int s = wbase + i * 4 + r;        // this lane's row
        const f32x4 v = in4[(rowbase + wbase + i * 4) * 16 + lane]; // 1KB/wave
        out4[(rowbase + s) * 80 + c4] = v;      // PLAIN store (L2/L3-absorbed)

        acc[0] += v;
        acc[1] += v * v;

        f32x4 pv = shfl4(v, lane - 16);         // previous row (r>=1)
        if (r == 0) pv = prev_top;
        if (s > 0) {
            const f32x4 d = v - pv;
            acc[2] += vmax0(d);
            acc[3] += vmax0(-d);
        }
        prev_top = shfl4(v, 48 + c4);           // group's last row, next iter

        if (s >= S - 26) {
            acc[5] += v;
            if (s >= S - 12) acc[4] += v;
        }
    }

    // Cross-slice reduce in LDS: lds[p][sl][ch], sl = tid>>4 = w*4+r
    __shared__ float lds[6][16][64];
    const int sl = tid >> 4;
    #pragma unroll
    for (int p = 0; p < 6; ++p) *(f32x4*)&lds[p][sl][c4 * 4] = acc[p];
    __syncthreads();

    if (tid < 64) {
        const size_t idx = ((size_t)(b * NCHUNK + chunk)) * 64 + tid;
        #pragma unroll
        for (int p = 0; p < 6; ++p) {
            float t = 0.f;
            #pragma unroll
            for (int s2 = 0; s2 < 16; ++s2) t += lds[p][s2][tid];
            part[(size_t)p * PSTRIDE + idx] = t;
        }
    }
}

// K2: fold partials -> stats (redundantly per block) + broadcast channels
// [64,320). 2048 blocks x 256 threads; block = (b, 128-row segment).
// NT stores (r8 A/B: plain stores cost ~10 us on this 256MB stream).
__global__ __launch_bounds__(256) void ti_stats_broadcast(const float* __restrict__ part,
                                                          f32x4* __restrict__ out4) {
    const int blk  = blockIdx.x;
    const int b    = blk >> 5;          // 0..63
    const int seg  = blk & 31;          // 0..31 (128 rows each)
    const int tid  = threadIdx.x;
    const int w    = tid >> 6;          // wave 0..3
    const int lane = tid & 63;

    __shared__ float sums[6][64];
    __shared__ f32x4 st4[4][16];

    // ---- fold partials for this b: plane w (+ planes 4,5 on waves 0,1) ----
    {
        float a = 0.f;
        #pragma unroll
        for (int ch = 0; ch < NCHUNK; ++ch)
            a += part[(size_t)w * PSTRIDE + (size_t)(b * NCHUNK + ch) * 64 + lane];
        sums[w][lane] = a;
        if (w < 2) {
            const int p1 = 4 + w;
            float a2 = 0.f;
            #pragma unroll
            for (int ch = 0; ch < NCHUNK; ++ch)
                a2 += part[(size_t)p1 * PSTRIDE + (size_t)(b * NCHUNK + ch) * 64 + lane];
            sums[p1][lane] = a2;
        }
    }
    __syncthreads();

    if (tid < 64) {
        const float sum = sums[0][tid], sumsq = sums[1][tid];
        const float gain = sums[2][tid], loss = sums[3][tid];
        const float s12 = sums[4][tid], s26 = sums[5][tid];

        const float inv_sm1 = 1.f / (float)(S - 1);
        const float ag = gain * inv_sm1;
        const float al = loss * inv_sm1;
        const float rs = ag / (al + 1e-7f);
        const float rsi = 100.f - 100.f / (1.f + rs);

        const float macd = s12 * (1.f / 12.f) - s26 * (1.f / 26.f);

        const float sma = sum * (1.f / (float)S);
        const float var = sumsq * (1.f / (float)S) - sma * sma;
        const float sd = sqrtf(fmaxf(var, 0.f));

        float* stf = (float*)st4;   // stf[which*64 + c]
        stf[0 * 64 + tid] = rsi;
        stf[1 * 64 + tid] = macd;
        stf[2 * 64 + tid] = sma + 2.f * sd;
        stf[3 * 64 + tid] = sma - 2.f * sd;
    }
    __syncthreads();

    // ---- broadcast channels [64,320) for 128 rows, NT 1KB/wave runs ----
    const int q = lane;                 // 0..63, loop-invariant
    const f32x4 v = st4[q >> 4][q & 15];

    const size_t base_row = (size_t)b * S + (size_t)seg * 128;
    #pragma unroll 8
    for (int pass = 0; pass < 32; ++pass) {
        const size_t row = base_row + pass * 4 + w;   // 1KB contiguous per wave
        __builtin_nontemporal_store(v, &out4[row * 80 + 16 + q]);
    }
}

extern "C" void kernel_launch(void* const* d_in, const int* in_sizes, int n_in,
                              void* d_out, int out_size, void* d_ws, size_t ws_size,
                              hipStream_t stream) {
    const f32x4* in4 = (const f32x4*)d_in[0];
    f32x4* out4 = (f32x4*)d_out;
    float* part = (float*)d_ws;            // 6 * 65536 floats = 1.5 MB

    ti_copy_reduce<<<B * NCHUNK, 256, 0, stream>>>(in4, out4, part);
    ti_stats_broadcast<<<B * 32, 256, 0, stream>>>(part, out4);
}

// Round 14
// 79.869 us; speedup vs baseline: 1.0048x; 1.0048x over previous
//
#include <hip/hip_runtime.h>
#include <hip/hip_bf16.h>

// Problem constants (from setup_inputs): price_data float32 [64, 4096, 64]
#define B 64
#define S 4096
#define C 64
#define NCHUNK 16            // s-chunks per batch in K1; block = (b, chunk)
#define LCH (S / NCHUNK)     // 256 s per K1 block
#define SPT (LCH / 16)       // 16 s per thread-slice (16 slices per block)

// native clang vector type (usable with __builtin_nontemporal_store)
typedef float f32x4 __attribute__((ext_vector_type(4)));

// Partials in ws: part[p][ (b*NCHUNK + chunk)*64 + c ], p: 0=sum 1=sumsq
// 2=gain 3=loss 4=sum12 5=sum26
#define PSTRIDE ((size_t)B * NCHUNK * 64)   // 65536 floats per plane (1.5 MB total)

__device__ inline f32x4 vmax0(f32x4 a) {
    f32x4 r;
    r.x = fmaxf(a.x, 0.f);
    r.y = fmaxf(a.y, 0.f);
    r.z = fmaxf(a.z, 0.f);
    r.w = fmaxf(a.w, 0.f);
    return r;
}

// K1: PURE partial reduction (64 MB linear read -> 1.5 MB partials).
// 1024 blocks x 256 threads; proven ~11 us shape. Leaves input L3-resident.
__global__ __launch_bounds__(256) void ti_reduce(const f32x4* __restrict__ in4,
                                                 float* __restrict__ part) {
    const int b     = blockIdx.x / NCHUNK;
    const int chunk = blockIdx.x % NCHUNK;
    const int tid   = threadIdx.x;
    const int sl    = tid >> 4;     // s-slice 0..15
    const int c4    = tid & 15;     // float4 channel group 0..15
    const int s0    = chunk * LCH + sl * SPT;

    const size_t rowbase = (size_t)b * S;

    f32x4 acc[6];
    #pragma unroll
    for (int p = 0; p < 6; ++p) acc[p] = (f32x4){0.f, 0.f, 0.f, 0.f};

    f32x4 prev = (f32x4){0.f, 0.f, 0.f, 0.f};
    if (s0 > 0) prev = in4[(rowbase + s0 - 1) * 16 + c4];

    #pragma unroll 8
    for (int j = 0; j < SPT; ++j) {
        const int s = s0 + j;
        const f32x4 v = in4[(rowbase + s) * 16 + c4];
        acc[0] += v;
        acc[1] += v * v;
        if (s > 0) {
            const f32x4 d = v - prev;
            acc[2] += vmax0(d);
            acc[3] += vmax0(-d);
        }
        prev = v;
        if (s >= S - 26) {
            acc[5] += v;
            if (s >= S - 12) acc[4] += v;
        }
    }

    __shared__ float lds[6][16][64];
    #pragma unroll
    for (int p = 0; p < 6; ++p) *(f32x4*)&lds[p][sl][c4 * 4] = acc[p];
    __syncthreads();

    if (tid < 64) {
        const size_t idx = ((size_t)(b * NCHUNK + chunk)) * 64 + tid;
        #pragma unroll
        for (int p = 0; p < 6; ++p) {
            float t = 0.f;
            #pragma unroll
            for (int s2 = 0; s2 < 16; ++s2) t += lds[p][s2][tid];
            part[(size_t)p * PSTRIDE + idx] = t;
        }
    }
}

// K2: 2048 blocks x 384 threads (6 waves); block = (b, 128-row segment).
//  waves 0-3: fold partials -> stats -> broadcast channels [64,320)
//             (byte-identical to the proven 6.4 TB/s r6 writer).
//  waves 4-5: copy channels [0,64): 1KB wave-contiguous L3-hit loads ->
//             4x256B NT stores. Dedicated waves so the broadcast stream
//             NEVER stalls on a load. Copy split 8 iters before / 8 after
//             the fold barriers to overlap the fold.
__global__ __launch_bounds__(384) void ti_write(const f32x4* __restrict__ in4,
                                                const float* __restrict__ part,
                                                f32x4* __restrict__ out4) {
    const int blk  = blockIdx.x;
    const int b    = blk >> 5;          // 0..63
    const int seg  = blk & 31;          // 0..31 (128 rows each)
    const int tid  = threadIdx.x;
    const int w    = tid >> 6;          // wave 0..5
    const int lane = tid & 63;

    __shared__ float sums[6][64];
    __shared__ f32x4 st4[4][16];

    const size_t base_row = (size_t)b * S + (size_t)seg * 128;

    if (w < 4) {
        // ---- fold partials for this b: plane w (+ planes 4,5 on waves 0,1) ----
        float a = 0.f;
        #pragma unroll
        for (int ch = 0; ch < NCHUNK; ++ch)
            a += part[(size_t)w * PSTRIDE + (size_t)(b * NCHUNK + ch) * 64 + lane];
        sums[w][lane] = a;
        if (w < 2) {
            const int p1 = 4 + w;
            float a2 = 0.f;
            #pragma unroll
            for (int ch = 0; ch < NCHUNK; ++ch)
                a2 += part[(size_t)p1 * PSTRIDE + (size_t)(b * NCHUNK + ch) * 64 + lane];
            sums[p1][lane] = a2;
        }
    } else {
        // ---- copy, first half: iterations 0..7 ----
        const int cw = w - 4;           // 0..1
        #pragma unroll
        for (int i = 0; i < 8; ++i) {
            const size_t r0 = base_row + cw * 64 + i * 4;
            const f32x4 v = in4[r0 * 16 + lane];                 // 1KB/wave, L3 hit
            const size_t row = r0 + (lane >> 4);
            __builtin_nontemporal_store(v, &out4[row * 80 + (lane & 15)]);
        }
    }
    __syncthreads();

    if (tid < 64) {
        const float sum = sums[0][tid], sumsq = sums[1][tid];
        const float gain = sums[2][tid], loss = sums[3][tid];
        const float s12 = sums[4][tid], s26 = sums[5][tid];

        const float inv_sm1 = 1.f / (float)(S - 1);
        const float ag = gain * inv_sm1;
        const float al = loss * inv_sm1;
        const float rs = ag / (al + 1e-7f);
        const float rsi = 100.f - 100.f / (1.f + rs);

        const float macd = s12 * (1.f / 12.f) - s26 * (1.f / 26.f);

        const float sma = sum * (1.f / (float)S);
        const float var = sumsq * (1.f / (float)S) - sma * sma;
        const float sd = sqrtf(fmaxf(var, 0.f));

        float* stf = (float*)st4;   // stf[which*64 + c]
        stf[0 * 64 + tid] = rsi;
        stf[1 * 64 + tid] = macd;
        stf[2 * 64 + tid] = sma + 2.f * sd;
        stf[3 * 64 + tid] = sma - 2.f * sd;
    }
    __syncthreads();

    if (w < 4) {
        // ---- broadcast channels [64,320) for 128 rows, NT 1KB/wave runs ----
        const int q = lane;                 // 0..63, loop-invariant
        const f32x4 v = st4[q >> 4][q & 15];

        #pragma unroll 8
        for (int pass = 0; pass < 32; ++pass) {
            const size_t row = base_row + pass * 4 + w;
            __builtin_nontemporal_store(v, &out4[row * 80 + 16 + q]);
        }
    } else {
        // ---- copy, second half: iterations 8..15 ----
        const int cw = w - 4;
        #pragma unroll
        for (int i = 8; i < 16; ++i) {
            const size_t r0 = base_row + cw * 64 + i * 4;
            const f32x4 v = in4[r0 * 16 + lane];
            const size_t row = r0 + (lane >> 4);
            __builtin_nontemporal_store(v, &out4[row * 80 + (lane & 15)]);
        }
    }
}

extern "C" void kernel_launch(void* const* d_in, const int* in_sizes, int n_in,
                              void* d_out, int out_size, void* d_ws, size_t ws_size,
                              hipStream_t stream) {
    const f32x4* in4 = (const f32x4*)d_in[0];
    f32x4* out4 = (f32x4*)d_out;
    float* part = (float*)d_ws;            // 6 * 65536 floats = 1.5 MB

    ti_reduce<<<B * NCHUNK, 256, 0, stream>>>(in4, part);
    ti_write<<<B * 32, 384, 0, stream>>>(in4, part, out4);
}